// Round 1
// baseline (345.749 us; speedup 1.0000x reference)
//
#include <hip/hip_runtime.h>
#include <stdint.h>

typedef unsigned long long u64;
typedef unsigned int u32;

#define NB 8
#define NA 76725
#define NC 80
#define NCH 84
#define PRE_K 200
#define CAP 1024
#define T0 0.92f
#define TILE_A 1024
#define NTILES 75
#define MAXPC 100
#define MAXDET 100

// ---------- helpers ----------

__device__ __forceinline__ float sigmoid_ref(float x) {
    // match jax.nn.sigmoid = 1/(1+exp(-x)) in fp32 (no fast-math approx)
    return 1.0f / (1.0f + expf(-x));
}

// Decode one box exactly like the reference (fp32 ops, no fma contraction;
// anchor dims in double like the python host math, then cast to f32).
__device__ void decode_box(float4 d, int a, float4* box, float* areaOut) {
    int lvl, off, fw, stride;
    if (a < 57600)      { lvl = 0; off = 0;     fw = 80; stride = 8;   }
    else if (a < 72000) { lvl = 1; off = 57600; fw = 40; stride = 16;  }
    else if (a < 75600) { lvl = 2; off = 72000; fw = 20; stride = 32;  }
    else if (a < 76500) { lvl = 3; off = 75600; fw = 10; stride = 64;  }
    else                { lvl = 4; off = 76500; fw = 5;  stride = 128; }
    int idx  = a - off;
    int k    = idx % 9;
    int cell = idx / 9;
    int row = cell / fw, col = cell - row * fw;
    float cx = __fmul_rn((float)col + 0.5f, (float)stride);
    float cy = __fmul_rn((float)row + 0.5f, (float)stride);
    int ri = k / 3, si = k - ri * 3;
    double r    = (ri == 0) ? 0.5 : ((ri == 1) ? 1.0 : 2.0);
    double side = (double)(32 << lvl);
    double area = side * side;
    double h = sqrt(area / r);
    double w = area / h;
    double s = exp2((double)si / 3.0);
    float aw = (float)(s * w);
    float ah = (float)(s * h);
    // b = box_pred * BOX_VAR
    float b0 = __fmul_rn(d.x, 0.1f);
    float b1 = __fmul_rn(d.y, 0.1f);
    float b2 = __fmul_rn(d.z, 0.2f);
    float b3 = __fmul_rn(d.w, 0.2f);
    // xy = b[:2]*anchor_wh + anchor_cxy ; wh = exp(b[2:])*anchor_wh
    float ux = __fadd_rn(__fmul_rn(b0, aw), cx);
    float uy = __fadd_rn(__fmul_rn(b1, ah), cy);
    float wx = __fmul_rn(expf(b2), aw);
    float wy = __fmul_rn(expf(b3), ah);
    float hx = __fmul_rn(wx, 0.5f);
    float hy = __fmul_rn(wy, 0.5f);
    float x1 = __fsub_rn(ux, hx), y1 = __fsub_rn(uy, hy);
    float x2 = __fadd_rn(ux, hx), y2 = __fadd_rn(uy, hy);
    *box = make_float4(x1, y1, x2, y2);
    *areaOut = __fmul_rn(__fsub_rn(x2, x1), __fsub_rn(y2, y1));
}

__device__ __forceinline__ void bitonic_desc_1024(u64* keys) {
    for (u32 k = 2; k <= 1024u; k <<= 1) {
        for (u32 j = k >> 1; j > 0; j >>= 1) {
            for (u32 i = threadIdx.x; i < 1024u; i += 256u) {
                u32 ixj = i ^ j;
                if (ixj > i) {
                    u64 x = keys[i], y = keys[ixj];
                    if (((i & k) == 0u) ? (x < y) : (x > y)) {
                        keys[i] = y; keys[ixj] = x;
                    }
                }
            }
            __syncthreads();
        }
    }
}

// ---------- kernel 1: coalesced scan, sigmoid, candidate append ----------

__global__ __launch_bounds__(256) void k_scan(const float* __restrict__ pred,
                                              u64* __restrict__ cand,
                                              u32* __restrict__ cnt) {
    int b  = blockIdx.y;
    int t  = blockIdx.x;
    int a0 = t * TILE_A;
    int nA = NA - a0; if (nA > TILE_A) nA = TILE_A;
    long base = ((long)b * NA + a0) * NCH;
    const float4* p4 = (const float4*)(pred + base);
    int nf4 = nA * (NCH / 4);
    for (int i = threadIdx.x; i < nf4; i += 256) {
        float4 v = p4[i];
        float vv[4] = {v.x, v.y, v.z, v.w};
        int e0 = i * 4;
#pragma unroll
        for (int q = 0; q < 4; ++q) {
            int e   = e0 + q;
            u32 row = (u32)e / NCH;
            u32 ch  = (u32)e - row * NCH;
            if (ch >= 4u) {
                float sig = sigmoid_ref(vv[q]);
                if (sig > T0) {
                    int a  = a0 + (int)row;
                    int bc = b * NC + (int)(ch - 4u);
                    u32 pos = atomicAdd(&cnt[bc], 1u);
                    if (pos < CAP) {
                        cand[(long)bc * CAP + pos] =
                            ((u64)__float_as_uint(sig) << 32) | (u64)(~(u32)a);
                    }
                }
            }
        }
    }
}

// ---------- kernel 2: exact repair (only if static gate failed) ----------

__global__ __launch_bounds__(256) void k_repair(const float* __restrict__ pred,
                                                u64* __restrict__ cand,
                                                u32* __restrict__ cnt) {
    int bc = blockIdx.x;
    u32 c0 = cnt[bc];
    if (c0 >= (u32)PRE_K && c0 <= (u32)CAP) return;  // fast path OK
    int b = bc / NC, c = bc % NC;
    __shared__ u64 red[256];
    u64 cur = ~0ull;
    for (int k = 0; k < PRE_K; ++k) {
        u64 loc = 0;
        for (int a = threadIdx.x; a < NA; a += 256) {
            float x  = pred[((long)b * NA + a) * NCH + 4 + c];
            float sg = sigmoid_ref(x);
            u64 key  = ((u64)__float_as_uint(sg) << 32) | (u64)(~(u32)a);
            if (key < cur && key > loc) loc = key;
        }
        red[threadIdx.x] = loc;
        __syncthreads();
        for (int s = 128; s > 0; s >>= 1) {
            if (threadIdx.x < s) {
                if (red[threadIdx.x + s] > red[threadIdx.x])
                    red[threadIdx.x] = red[threadIdx.x + s];
            }
            __syncthreads();
        }
        cur = red[0];
        if (threadIdx.x == 0) cand[(long)bc * CAP + k] = cur;
        __syncthreads();
    }
    if (threadIdx.x == 0) cnt[bc] = PRE_K;
}

// ---------- kernel 3: per-(b,c) sort + NMS + per-class top-100 ----------

__global__ __launch_bounds__(256) void k_nms(const float* __restrict__ pred,
                                             const u64* __restrict__ cand,
                                             const u32* __restrict__ cnt,
                                             float* __restrict__ sc2,
                                             float* __restrict__ bb2) {
    int bc = blockIdx.x;
    int b  = bc / NC;
    __shared__ u64 keys[CAP];
    __shared__ float4 box[PRE_K];
    __shared__ float area[PRE_K];
    __shared__ u32 supp[PRE_K][7];
    __shared__ u32 keepw[7];

    int n = (int)cnt[bc]; if (n > CAP) n = CAP;
    for (int i = threadIdx.x; i < CAP; i += 256)
        keys[i] = (i < n) ? cand[(long)bc * CAP + i] : 0ull;
    __syncthreads();

    bitonic_desc_1024(keys);

    for (int i = threadIdx.x; i < PRE_K * 7; i += 256) supp[i / 7][i % 7] = 0u;
    if (threadIdx.x < 7) keepw[threadIdx.x] = 0u;
    __syncthreads();

    if (threadIdx.x < PRE_K) {
        int r   = threadIdx.x;
        u64 key = keys[r];
        float sig = __uint_as_float((u32)(key >> 32));
        int a = (int)(~(u32)key);
        float4 bx = make_float4(0.f, 0.f, 0.f, 0.f);
        float ar = 0.f;
        if (sig > 0.05f) {  // valid = sc > CONF_THR
            float4 dd = *(const float4*)(pred + ((long)b * NA + a) * NCH);
            decode_box(dd, a, &bx, &ar);
            atomicOr(&keepw[r >> 5], 1u << (r & 31));
        }
        box[r] = bx; area[r] = ar;
    }
    __syncthreads();

    // build suppression bitmask: bit j set for pairs j>i with IoU>0.5
    for (int p = threadIdx.x; p < PRE_K * PRE_K; p += 256) {
        int i  = p / PRE_K;
        int jx = p - i * PRE_K;
        if (jx > i) {
            float4 bi = box[i], bj = box[jx];
            float ltx = fmaxf(bi.x, bj.x), lty = fmaxf(bi.y, bj.y);
            float rbx = fminf(bi.z, bj.z), rby = fminf(bi.w, bj.w);
            float wx = fmaxf(__fsub_rn(rbx, ltx), 0.f);
            float wy = fmaxf(__fsub_rn(rby, lty), 0.f);
            float inter = __fmul_rn(wx, wy);
            float den = __fadd_rn(__fsub_rn(__fadd_rn(area[i], area[jx]), inter), 1e-8f);
            float iou = __fdiv_rn(inter, den);
            if (iou > 0.5f) atomicOr(&supp[i][jx >> 5], 1u << (jx & 31));
        }
    }
    __syncthreads();

    // serial greedy sweep (matches fori_loop exactly; ~1.4k ops)
    if (threadIdx.x == 0) {
        u32 kw[7];
#pragma unroll
        for (int w = 0; w < 7; ++w) kw[w] = keepw[w];
        for (int i = 0; i < PRE_K; ++i) {
            if ((kw[i >> 5] >> (i & 31)) & 1u) {
#pragma unroll
                for (int w = 0; w < 7; ++w) kw[w] &= ~supp[i][w];
            }
        }
#pragma unroll
        for (int w = 0; w < 7; ++w) keepw[w] = kw[w];
    }
    __syncthreads();

    // ordered compaction -> per-class top-100
    if (threadIdx.x < PRE_K) {
        int r = threadIdx.x;
        if ((keepw[r >> 5] >> (r & 31)) & 1u) {
            int pos = 0;
            for (int w = 0; w < (r >> 5); ++w) pos += __popc(keepw[w]);
            pos += __popc(keepw[r >> 5] & ((1u << (r & 31)) - 1u));
            if (pos < MAXPC) {
                u64 key = keys[r];
                float sig = __uint_as_float((u32)(key >> 32));
                sc2[bc * MAXPC + pos] = sig;
                float4 bx = box[r];
                float* o = bb2 + ((long)bc * MAXPC + pos) * 4;
                o[0] = bx.x; o[1] = bx.y; o[2] = bx.z; o[3] = bx.w;
            }
        }
    }
}

// ---------- kernel 4: per-image final top-100 + outputs ----------

__global__ __launch_bounds__(256) void k_final(const float* __restrict__ sc2,
                                               const float* __restrict__ bb2,
                                               float* __restrict__ out) {
    int b = blockIdx.x;
    __shared__ u32 hist[256];
    __shared__ u64 keys[CAP];
    __shared__ u32 cnt_s;
    __shared__ int t_s;
    for (int i = threadIdx.x; i < 256; i += 256) hist[i] = 0u;
    if (threadIdx.x == 0) cnt_s = 0u;
    __syncthreads();

    const float* s_b = sc2 + b * (NC * MAXPC);
    for (int f = threadIdx.x; f < NC * MAXPC; f += 256) {
        float s = s_b[f];
        if (s > 0.f) {
            int bin = (int)(s * 256.f); if (bin > 255) bin = 255;
            atomicAdd(&hist[bin], 1u);
        }
    }
    __syncthreads();
    if (threadIdx.x == 0) {
        u32 cum = 0; int t = 0;
        for (int bin = 255; bin >= 0; --bin) {
            cum += hist[bin];
            if (cum >= (u32)MAXDET) { t = bin; break; }
        }
        t_s = t;
    }
    __syncthreads();
    int t = t_s;
    for (int f = threadIdx.x; f < NC * MAXPC; f += 256) {
        float s = s_b[f];
        if (s > 0.f) {
            int bin = (int)(s * 256.f); if (bin > 255) bin = 255;
            if (bin >= t) {
                u32 pos = atomicAdd(&cnt_s, 1u);
                if (pos < CAP)
                    keys[pos] = ((u64)__float_as_uint(s) << 32) | (u64)(~(u32)f);
            }
        }
    }
    __syncthreads();
    u32 g = cnt_s; if (g > (u32)CAP) g = CAP;
    for (int i = threadIdx.x; i < CAP; i += 256)
        if (i >= (int)g) keys[i] = 0ull;
    __syncthreads();

    bitonic_desc_1024(keys);

    if (threadIdx.x < MAXDET) {
        int r = threadIdx.x;
        u64 key = keys[r];
        u32 hi = (u32)(key >> 32);
        if (hi != 0u) {
            float s = __uint_as_float(hi);
            int f = (int)(~(u32)key);
            int c = f / MAXPC, jj = f - c * MAXPC;
            const float* bsrc = bb2 + ((long)(b * NC + c) * MAXPC + jj) * 4;
            float* ob = out + ((long)b * MAXDET + r) * 4;
            ob[0] = bsrc[0]; ob[1] = bsrc[1]; ob[2] = bsrc[2]; ob[3] = bsrc[3];
            out[NB * MAXDET * 4 + b * MAXDET + r] = s;
            out[NB * MAXDET * 4 + NB * MAXDET + b * MAXDET + r] = (float)c;
        }
    }
    __syncthreads();
    if (threadIdx.x == 0) {
        int nv = 0;
        for (int r = 0; r < MAXDET; ++r)
            if ((u32)(keys[r] >> 32) != 0u) ++nv;
        out[NB * MAXDET * 4 + 2 * NB * MAXDET + b] = (float)nv;
    }
}

// ---------- launcher ----------

extern "C" void kernel_launch(void* const* d_in, const int* in_sizes, int n_in,
                              void* d_out, int out_size, void* d_ws, size_t ws_size,
                              hipStream_t stream) {
    // inputs: images [8,640,640,3] (unused), predictions [8,76725,84]
    const float* pred = (const float*)d_in[1];
    if (n_in >= 2 && in_sizes[0] == NB * NA * NCH) pred = (const float*)d_in[0];

    char* ws = (char*)d_ws;
    const long BCN = (long)NB * NC;
    u64* cand = (u64*)ws;                                     // 640*1024*8 B
    u32* cnt  = (u32*)(ws + BCN * CAP * 8);                   // 640*4 B
    float* sc2 = (float*)(ws + BCN * CAP * 8 + BCN * 4);      // 640*100*4 B
    float* bb2 = sc2 + BCN * MAXPC;                           // 640*100*16 B

    size_t zero_bytes = (size_t)BCN * 4 + (size_t)BCN * MAXPC * 4 + (size_t)BCN * MAXPC * 16;
    hipMemsetAsync(cnt, 0, zero_bytes, stream);
    hipMemsetAsync(d_out, 0, (size_t)out_size * 4, stream);

    k_scan  <<<dim3(NTILES, NB), 256, 0, stream>>>(pred, cand, cnt);
    k_repair<<<dim3(NB * NC),    256, 0, stream>>>(pred, cand, cnt);
    k_nms   <<<dim3(NB * NC),    256, 0, stream>>>(pred, cand, cnt, sc2, bb2);
    k_final <<<dim3(NB),         256, 0, stream>>>(sc2, bb2, (float*)d_out);
}

// Round 2
// 312.390 us; speedup vs baseline: 1.1068x; 1.1068x over previous
//
#include <hip/hip_runtime.h>
#include <stdint.h>

typedef unsigned long long u64;
typedef unsigned int u32;

#define NB 8
#define NA 76725
#define NC 80
#define NCH 84
#define PRE_K 200
#define CAP 1024
#define T0 0.92f
#define XCUT 2.40f
#define MAXPC 100
#define MAXDET 100
#define F4_PER_IMG (NA * 21u)   // 1,611,225 float4 per image (84 floats = 21 float4/anchor)

// ---------- helpers ----------

__device__ __forceinline__ float sigmoid_ref(float x) {
    // match jax.nn.sigmoid = 1/(1+exp(-x)) in fp32 (no fast-math approx)
    return 1.0f / (1.0f + expf(-x));
}

// Decode one box exactly like the reference (fp32 ops, no fma contraction;
// anchor dims in double like the python host math, then cast to f32).
__device__ void decode_box(float4 d, int a, float4* box, float* areaOut) {
    int lvl, off, fw, stride;
    if (a < 57600)      { lvl = 0; off = 0;     fw = 80; stride = 8;   }
    else if (a < 72000) { lvl = 1; off = 57600; fw = 40; stride = 16;  }
    else if (a < 75600) { lvl = 2; off = 72000; fw = 20; stride = 32;  }
    else if (a < 76500) { lvl = 3; off = 75600; fw = 10; stride = 64;  }
    else                { lvl = 4; off = 76500; fw = 5;  stride = 128; }
    int idx  = a - off;
    int k    = idx % 9;
    int cell = idx / 9;
    int row = cell / fw, col = cell - row * fw;
    float cx = __fmul_rn((float)col + 0.5f, (float)stride);
    float cy = __fmul_rn((float)row + 0.5f, (float)stride);
    int ri = k / 3, si = k - ri * 3;
    double r    = (ri == 0) ? 0.5 : ((ri == 1) ? 1.0 : 2.0);
    double side = (double)(32 << lvl);
    double area = side * side;
    double h = sqrt(area / r);
    double w = area / h;
    double s = exp2((double)si / 3.0);
    float aw = (float)(s * w);
    float ah = (float)(s * h);
    float b0 = __fmul_rn(d.x, 0.1f);
    float b1 = __fmul_rn(d.y, 0.1f);
    float b2 = __fmul_rn(d.z, 0.2f);
    float b3 = __fmul_rn(d.w, 0.2f);
    float ux = __fadd_rn(__fmul_rn(b0, aw), cx);
    float uy = __fadd_rn(__fmul_rn(b1, ah), cy);
    float wx = __fmul_rn(expf(b2), aw);
    float wy = __fmul_rn(expf(b3), ah);
    float hx = __fmul_rn(wx, 0.5f);
    float hy = __fmul_rn(wy, 0.5f);
    float x1 = __fsub_rn(ux, hx), y1 = __fsub_rn(uy, hy);
    float x2 = __fadd_rn(ux, hx), y2 = __fadd_rn(uy, hy);
    *box = make_float4(x1, y1, x2, y2);
    *areaOut = __fmul_rn(__fsub_rn(x2, x1), __fsub_rn(y2, y1));
}

__device__ __forceinline__ void bitonic_desc_1024(u64* keys) {
    for (u32 k = 2; k <= 1024u; k <<= 1) {
        for (u32 j = k >> 1; j > 0; j >>= 1) {
            for (u32 i = threadIdx.x; i < 1024u; i += blockDim.x) {
                u32 ixj = i ^ j;
                if (ixj > i) {
                    u64 x = keys[i], y = keys[ixj];
                    if (((i & k) == 0u) ? (x < y) : (x > y)) {
                        keys[i] = y; keys[ixj] = x;
                    }
                }
            }
            __syncthreads();
        }
    }
}

// ---------- kernel 1: coalesced grid-stride scan + raw-logit prefilter ----------

__global__ __launch_bounds__(256) void k_scan(const float4* __restrict__ p4,
                                              u64* __restrict__ cand,
                                              u32* __restrict__ cnt) {
    u32 b = blockIdx.y;
    const float4* base = p4 + (u64)b * F4_PER_IMG;
    u32 stride = gridDim.x * 256u;
    for (u32 i = blockIdx.x * 256u + threadIdx.x; i < F4_PER_IMG; i += stride) {
        float4 v = base[i];
        u32 a  = i / 21u;
        u32 c4 = i - a * 21u;
        if (c4 == 0u) continue;            // float4 #0 of each anchor = box channels
        u32 cbase = c4 * 4u - 4u;          // class index of v.x
        float vv[4] = {v.x, v.y, v.z, v.w};
#pragma unroll
        for (int q = 0; q < 4; ++q) {
            if (vv[q] > XCUT) {            // sigmoid>0.92 => x>2.4423; 2.40 is conservative
                float sig = sigmoid_ref(vv[q]);
                if (sig > T0) {
                    u32 bc = b * NC + cbase + (u32)q;
                    u32 pos = atomicAdd(&cnt[bc], 1u);
                    if (pos < CAP)
                        cand[(u64)bc * CAP + pos] =
                            ((u64)__float_as_uint(sig) << 32) | (u64)(~a);
                }
            }
        }
    }
}

// ---------- kernel 2: exact repair (only if static gate failed) ----------

__global__ __launch_bounds__(256) void k_repair(const float* __restrict__ pred,
                                                u64* __restrict__ cand,
                                                u32* __restrict__ cnt) {
    int bc = blockIdx.x;
    u32 c0 = cnt[bc];
    if (c0 >= (u32)PRE_K && c0 <= (u32)CAP) return;  // fast path OK
    int b = bc / NC, c = bc % NC;
    __shared__ u64 red[256];
    u64 cur = ~0ull;
    for (int k = 0; k < PRE_K; ++k) {
        u64 loc = 0;
        for (int a = threadIdx.x; a < NA; a += 256) {
            float x  = pred[((long)b * NA + a) * NCH + 4 + c];
            float sg = sigmoid_ref(x);
            u64 key  = ((u64)__float_as_uint(sg) << 32) | (u64)(~(u32)a);
            if (key < cur && key > loc) loc = key;
        }
        red[threadIdx.x] = loc;
        __syncthreads();
        for (int s = 128; s > 0; s >>= 1) {
            if (threadIdx.x < s) {
                if (red[threadIdx.x + s] > red[threadIdx.x])
                    red[threadIdx.x] = red[threadIdx.x + s];
            }
            __syncthreads();
        }
        cur = red[0];
        if (threadIdx.x == 0) cand[(long)bc * CAP + k] = cur;
        __syncthreads();
    }
    if (threadIdx.x == 0) cnt[bc] = PRE_K;
}

// ---------- kernel 3: per-(b,c) sort + NMS + per-class top-100 ----------

__global__ __launch_bounds__(1024) void k_nms(const float* __restrict__ pred,
                                              const u64* __restrict__ cand,
                                              const u32* __restrict__ cnt,
                                              float* __restrict__ sc2,
                                              float* __restrict__ bb2) {
    int bc = blockIdx.x;
    int b  = bc / NC;
    __shared__ u64 keys[CAP];
    __shared__ float4 box[PRE_K];
    __shared__ float area[PRE_K];
    __shared__ u32 supp[PRE_K][7];
    __shared__ u32 keepw[7];

    int n = (int)cnt[bc]; if (n > CAP) n = CAP;
    for (int i = threadIdx.x; i < CAP; i += blockDim.x)
        keys[i] = (i < n) ? cand[(long)bc * CAP + i] : 0ull;
    __syncthreads();

    bitonic_desc_1024(keys);

    for (int i = threadIdx.x; i < PRE_K * 7; i += blockDim.x) supp[i / 7][i % 7] = 0u;
    if (threadIdx.x < 7) keepw[threadIdx.x] = 0u;
    __syncthreads();

    if (threadIdx.x < PRE_K) {
        int r   = threadIdx.x;
        u64 key = keys[r];
        float sig = __uint_as_float((u32)(key >> 32));
        int a = (int)(~(u32)key);
        float4 bx = make_float4(0.f, 0.f, 0.f, 0.f);
        float ar = 0.f;
        if (sig > 0.05f) {  // valid = sc > CONF_THR
            float4 dd = *(const float4*)(pred + ((long)b * NA + a) * NCH);
            decode_box(dd, a, &bx, &ar);
            atomicOr(&keepw[r >> 5], 1u << (r & 31));
        }
        box[r] = bx; area[r] = ar;
    }
    __syncthreads();

    // build suppression bitmask: bit j set for pairs j>i with IoU>0.5
    for (int p = threadIdx.x; p < PRE_K * PRE_K; p += blockDim.x) {
        int i  = p / PRE_K;
        int jx = p - i * PRE_K;
        if (jx > i) {
            float4 bi = box[i], bj = box[jx];
            float ltx = fmaxf(bi.x, bj.x), lty = fmaxf(bi.y, bj.y);
            float rbx = fminf(bi.z, bj.z), rby = fminf(bi.w, bj.w);
            float wx = fmaxf(__fsub_rn(rbx, ltx), 0.f);
            float wy = fmaxf(__fsub_rn(rby, lty), 0.f);
            float inter = __fmul_rn(wx, wy);
            float den = __fadd_rn(__fsub_rn(__fadd_rn(area[i], area[jx]), inter), 1e-8f);
            float iou = __fdiv_rn(inter, den);
            if (iou > 0.5f) atomicOr(&supp[i][jx >> 5], 1u << (jx & 31));
        }
    }
    __syncthreads();

    // serial greedy sweep (matches fori_loop exactly; ~1.4k ops)
    if (threadIdx.x == 0) {
        u32 kw[7];
#pragma unroll
        for (int w = 0; w < 7; ++w) kw[w] = keepw[w];
        for (int i = 0; i < PRE_K; ++i) {
            if ((kw[i >> 5] >> (i & 31)) & 1u) {
#pragma unroll
                for (int w = 0; w < 7; ++w) kw[w] &= ~supp[i][w];
            }
        }
#pragma unroll
        for (int w = 0; w < 7; ++w) keepw[w] = kw[w];
    }
    __syncthreads();

    // ordered compaction -> per-class top-100
    if (threadIdx.x < PRE_K) {
        int r = threadIdx.x;
        if ((keepw[r >> 5] >> (r & 31)) & 1u) {
            int pos = 0;
            for (int w = 0; w < (r >> 5); ++w) pos += __popc(keepw[w]);
            pos += __popc(keepw[r >> 5] & ((1u << (r & 31)) - 1u));
            if (pos < MAXPC) {
                u64 key = keys[r];
                float sig = __uint_as_float((u32)(key >> 32));
                sc2[bc * MAXPC + pos] = sig;
                float4 bx = box[r];
                float* o = bb2 + ((long)bc * MAXPC + pos) * 4;
                o[0] = bx.x; o[1] = bx.y; o[2] = bx.z; o[3] = bx.w;
            }
        }
    }
}

// ---------- kernel 4: per-image final top-100 + outputs ----------

__global__ __launch_bounds__(1024) void k_final(const float* __restrict__ sc2,
                                                const float* __restrict__ bb2,
                                                float* __restrict__ out) {
    int b = blockIdx.x;
    __shared__ u32 hist[256];
    __shared__ u64 keys[CAP];
    __shared__ u32 cnt_s;
    __shared__ int t_s;
    for (int i = threadIdx.x; i < 256; i += blockDim.x) hist[i] = 0u;
    if (threadIdx.x == 0) cnt_s = 0u;
    __syncthreads();

    const float* s_b = sc2 + b * (NC * MAXPC);
    for (int f = threadIdx.x; f < NC * MAXPC; f += blockDim.x) {
        float s = s_b[f];
        if (s > 0.f) {
            int bin = (int)(s * 256.f); if (bin > 255) bin = 255;
            atomicAdd(&hist[bin], 1u);
        }
    }
    __syncthreads();
    if (threadIdx.x == 0) {
        u32 cum = 0; int t = 0;
        for (int bin = 255; bin >= 0; --bin) {
            cum += hist[bin];
            if (cum >= (u32)MAXDET) { t = bin; break; }
        }
        t_s = t;
    }
    __syncthreads();
    int t = t_s;
    for (int f = threadIdx.x; f < NC * MAXPC; f += blockDim.x) {
        float s = s_b[f];
        if (s > 0.f) {
            int bin = (int)(s * 256.f); if (bin > 255) bin = 255;
            if (bin >= t) {
                u32 pos = atomicAdd(&cnt_s, 1u);
                if (pos < CAP)
                    keys[pos] = ((u64)__float_as_uint(s) << 32) | (u64)(~(u32)f);
            }
        }
    }
    __syncthreads();
    u32 g = cnt_s; if (g > (u32)CAP) g = CAP;
    for (int i = threadIdx.x; i < CAP; i += blockDim.x)
        if (i >= (int)g) keys[i] = 0ull;
    __syncthreads();

    bitonic_desc_1024(keys);

    if (threadIdx.x < MAXDET) {
        int r = threadIdx.x;
        u64 key = keys[r];
        u32 hi = (u32)(key >> 32);
        if (hi != 0u) {
            float s = __uint_as_float(hi);
            int f = (int)(~(u32)key);
            int c = f / MAXPC, jj = f - c * MAXPC;
            const float* bsrc = bb2 + ((long)(b * NC + c) * MAXPC + jj) * 4;
            float* ob = out + ((long)b * MAXDET + r) * 4;
            ob[0] = bsrc[0]; ob[1] = bsrc[1]; ob[2] = bsrc[2]; ob[3] = bsrc[3];
            out[NB * MAXDET * 4 + b * MAXDET + r] = s;
            out[NB * MAXDET * 4 + NB * MAXDET + b * MAXDET + r] = (float)c;
        }
    }
    __syncthreads();
    if (threadIdx.x == 0) {
        int nv = 0;
        for (int r = 0; r < MAXDET; ++r)
            if ((u32)(keys[r] >> 32) != 0u) ++nv;
        out[NB * MAXDET * 4 + 2 * NB * MAXDET + b] = (float)nv;
    }
}

// ---------- launcher ----------

extern "C" void kernel_launch(void* const* d_in, const int* in_sizes, int n_in,
                              void* d_out, int out_size, void* d_ws, size_t ws_size,
                              hipStream_t stream) {
    // inputs: images [8,640,640,3] (unused), predictions [8,76725,84]
    const float* pred = (const float*)d_in[1];
    if (n_in >= 2 && in_sizes[0] == NB * NA * NCH) pred = (const float*)d_in[0];

    char* ws = (char*)d_ws;
    const long BCN = (long)NB * NC;
    u64* cand = (u64*)ws;                                     // 640*1024*8 B
    u32* cnt  = (u32*)(ws + BCN * CAP * 8);                   // 640*4 B
    float* sc2 = (float*)(ws + BCN * CAP * 8 + BCN * 4);      // 640*100*4 B
    float* bb2 = sc2 + BCN * MAXPC;                           // 640*100*16 B

    size_t zero_bytes = (size_t)BCN * 4 + (size_t)BCN * MAXPC * 4 + (size_t)BCN * MAXPC * 16;
    hipMemsetAsync(cnt, 0, zero_bytes, stream);
    hipMemsetAsync(d_out, 0, (size_t)out_size * 4, stream);

    k_scan  <<<dim3(256, NB), 256, 0, stream>>>((const float4*)pred, cand, cnt);
    k_repair<<<dim3(NB * NC), 256, 0, stream>>>(pred, cand, cnt);
    k_nms   <<<dim3(NB * NC), 1024, 0, stream>>>(pred, cand, cnt, sc2, bb2);
    k_final <<<dim3(NB),      1024, 0, stream>>>(sc2, bb2, (float*)d_out);
}

// Round 3
// 177.512 us; speedup vs baseline: 1.9478x; 1.7598x over previous
//
#include <hip/hip_runtime.h>
#include <stdint.h>

typedef unsigned long long u64;
typedef unsigned int u32;

#define NB 8
#define NA 76725
#define NC 80
#define NCH 84
#define PRE_K 200
#define CAP 1024
#define T0 0.92f
#define XCUT 2.40f
#define MAXPC 100
#define MAXDET 100
#define F4_PER_IMG (NA * 21u)   // 1,611,225 float4 per image

#define NSH 8                   // counter shards per (b,c)
#define SCAP 128                // slots per shard  (8*128 = 1024 = CAP)
#define LCAP 24                 // LDS per-class list cap per block
#define BLKX 128                // blocks per image
#define SPAN (BLKX * 256u)      // grid-stride span in float4
#define FULLS 12                // 12 * 4 * SPAN = 1,572,864 <= F4_PER_IMG

// ---------- helpers ----------

__device__ __forceinline__ float sigmoid_ref(float x) {
    // match jax.nn.sigmoid = 1/(1+exp(-x)) in fp32 (no fast-math approx)
    return 1.0f / (1.0f + expf(-x));
}

// Decode one box exactly like the reference (fp32 ops, no fma contraction;
// anchor dims in double like the python host math, then cast to f32).
__device__ void decode_box(float4 d, int a, float4* box, float* areaOut) {
    int lvl, off, fw, stride;
    if (a < 57600)      { lvl = 0; off = 0;     fw = 80; stride = 8;   }
    else if (a < 72000) { lvl = 1; off = 57600; fw = 40; stride = 16;  }
    else if (a < 75600) { lvl = 2; off = 72000; fw = 20; stride = 32;  }
    else if (a < 76500) { lvl = 3; off = 75600; fw = 10; stride = 64;  }
    else                { lvl = 4; off = 76500; fw = 5;  stride = 128; }
    int idx  = a - off;
    int k    = idx % 9;
    int cell = idx / 9;
    int row = cell / fw, col = cell - row * fw;
    float cx = __fmul_rn((float)col + 0.5f, (float)stride);
    float cy = __fmul_rn((float)row + 0.5f, (float)stride);
    int ri = k / 3, si = k - ri * 3;
    double r    = (ri == 0) ? 0.5 : ((ri == 1) ? 1.0 : 2.0);
    double side = (double)(32 << lvl);
    double area = side * side;
    double h = sqrt(area / r);
    double w = area / h;
    double s = exp2((double)si / 3.0);
    float aw = (float)(s * w);
    float ah = (float)(s * h);
    float b0 = __fmul_rn(d.x, 0.1f);
    float b1 = __fmul_rn(d.y, 0.1f);
    float b2 = __fmul_rn(d.z, 0.2f);
    float b3 = __fmul_rn(d.w, 0.2f);
    float ux = __fadd_rn(__fmul_rn(b0, aw), cx);
    float uy = __fadd_rn(__fmul_rn(b1, ah), cy);
    float wx = __fmul_rn(expf(b2), aw);
    float wy = __fmul_rn(expf(b3), ah);
    float hx = __fmul_rn(wx, 0.5f);
    float hy = __fmul_rn(wy, 0.5f);
    float x1 = __fsub_rn(ux, hx), y1 = __fsub_rn(uy, hy);
    float x2 = __fadd_rn(ux, hx), y2 = __fadd_rn(uy, hy);
    *box = make_float4(x1, y1, x2, y2);
    *areaOut = __fmul_rn(__fsub_rn(x2, x1), __fsub_rn(y2, y1));
}

__device__ __forceinline__ void bitonic_desc_1024(u64* keys) {
    for (u32 k = 2; k <= 1024u; k <<= 1) {
        for (u32 j = k >> 1; j > 0; j >>= 1) {
            for (u32 i = threadIdx.x; i < 1024u; i += blockDim.x) {
                u32 ixj = i ^ j;
                if (ixj > i) {
                    u64 x = keys[i], y = keys[ixj];
                    if (((i & k) == 0u) ? (x < y) : (x > y)) {
                        keys[i] = y; keys[ixj] = x;
                    }
                }
            }
            __syncthreads();
        }
    }
}

// ---------- kernel 1: streaming scan, LDS-staged candidates ----------

__device__ __forceinline__ void scan4(float4 v, u32 idx, u32 b, u32 sh,
                                      u32* lhist, u64 (*llist)[LCAP],
                                      u64* __restrict__ cand,
                                      u32* __restrict__ cnt) {
    u32 a  = idx / 21u;
    u32 c4 = idx - a * 21u;
    if (c4 == 0u) return;                        // box channels
    float m = fmaxf(fmaxf(v.x, v.y), fmaxf(v.z, v.w));
    if (m <= XCUT) return;                       // sigmoid(2.4423)=0.92; 2.40 conservative
    u32 cb = c4 * 4u - 4u;
    float vv[4] = {v.x, v.y, v.z, v.w};
#pragma unroll
    for (int q = 0; q < 4; ++q) {
        if (vv[q] > XCUT) {
            float sig = sigmoid_ref(vv[q]);
            if (sig > T0) {
                u32 c = cb + (u32)q;
                u64 key = ((u64)__float_as_uint(sig) << 32) | (u64)(~a);
                u32 p = atomicAdd(&lhist[c], 1u);
                if (p < LCAP) {
                    llist[c][p] = key;
                } else {                          // rare overflow: direct global
                    u32 bcsh = (b * NC + c) * NSH + sh;
                    u32 g = atomicAdd(&cnt[bcsh], 1u);
                    if (g < SCAP) cand[(u64)bcsh * SCAP + g] = key;
                }
            }
        }
    }
}

__global__ __launch_bounds__(256) void k_scan(const float4* __restrict__ p4,
                                              u64* __restrict__ cand,
                                              u32* __restrict__ cnt) {
    __shared__ u32 lhist[NC];
    __shared__ u64 llist[NC][LCAP];
    u32 b  = blockIdx.y;
    u32 sh = blockIdx.x & (NSH - 1u);
    for (u32 c = threadIdx.x; c < NC; c += 256u) lhist[c] = 0u;
    __syncthreads();

    const float4* base = p4 + (u64)b * F4_PER_IMG;
    u32 i = blockIdx.x * 256u + threadIdx.x;
#pragma unroll 1
    for (int s = 0; s < FULLS; ++s, i += 4u * SPAN) {
        float4 v0 = base[i];
        float4 v1 = base[i + SPAN];
        float4 v2 = base[i + 2u * SPAN];
        float4 v3 = base[i + 3u * SPAN];
        scan4(v0, i,            b, sh, lhist, llist, cand, cnt);
        scan4(v1, i + SPAN,     b, sh, lhist, llist, cand, cnt);
        scan4(v2, i + 2u*SPAN,  b, sh, lhist, llist, cand, cnt);
        scan4(v3, i + 3u*SPAN,  b, sh, lhist, llist, cand, cnt);
    }
    for (; i < F4_PER_IMG; i += SPAN)
        scan4(base[i], i, b, sh, lhist, llist, cand, cnt);
    __syncthreads();

    // flush: one global atomic per touched class
    for (u32 c = threadIdx.x; c < NC; c += 256u) {
        u32 n = lhist[c]; if (n > LCAP) n = LCAP;
        if (n) {
            u32 bcsh = (b * NC + c) * NSH + sh;
            u32 base0 = atomicAdd(&cnt[bcsh], n);
            u64* seg = cand + (u64)bcsh * SCAP;
            for (u32 j = 0; j < n; ++j) {
                u32 p = base0 + j;
                if (p < SCAP) seg[p] = llist[c][j];
            }
        }
    }
}

// ---------- kernel 2: exact repair (only if fast-path gate failed) ----------

__global__ __launch_bounds__(256) void k_repair(const float* __restrict__ pred,
                                                u64* __restrict__ cand,
                                                u32* __restrict__ cnt,
                                                u32* __restrict__ rflag) {
    int bc = blockIdx.x;
    u32 total = 0; bool over = false;
    for (int s = 0; s < NSH; ++s) {
        u32 n = cnt[bc * NSH + s];
        if (n > (u32)SCAP) over = true;
        total += n;
    }
    if (!over && total >= (u32)PRE_K) return;    // fast path exact
    int b = bc / NC, c = bc % NC;
    u64* cseg = cand + (u64)bc * (NSH * SCAP);
    __shared__ u64 red[256];
    u64 cur = ~0ull;
    for (int k = 0; k < PRE_K; ++k) {
        u64 loc = 0;
        for (int a = threadIdx.x; a < NA; a += 256) {
            float x  = pred[((long)b * NA + a) * NCH + 4 + c];
            float sg = sigmoid_ref(x);
            u64 key  = ((u64)__float_as_uint(sg) << 32) | (u64)(~(u32)a);
            if (key < cur && key > loc) loc = key;
        }
        red[threadIdx.x] = loc;
        __syncthreads();
        for (int s = 128; s > 0; s >>= 1) {
            if (threadIdx.x < s) {
                if (red[threadIdx.x + s] > red[threadIdx.x])
                    red[threadIdx.x] = red[threadIdx.x + s];
            }
            __syncthreads();
        }
        cur = red[0];
        if (threadIdx.x == 0) cseg[k] = cur;
        __syncthreads();
    }
    if (threadIdx.x == 0) rflag[bc] = 1u;
}

// ---------- kernel 3: per-(b,c) sort + NMS + per-class top-100 ----------

__global__ __launch_bounds__(1024) void k_nms(const float* __restrict__ pred,
                                              const u64* __restrict__ cand,
                                              const u32* __restrict__ cnt,
                                              const u32* __restrict__ rflag,
                                              float* __restrict__ sc2,
                                              float* __restrict__ bb2) {
    int bc = blockIdx.x;
    int b  = bc / NC;
    __shared__ u64 keys[CAP];
    __shared__ float4 box[PRE_K];
    __shared__ float area[PRE_K];
    __shared__ u32 supp[PRE_K][7];
    __shared__ u32 keepw[7];

    const u64* cseg = cand + (u64)bc * (NSH * SCAP);
    u32 rep = rflag[bc];
    for (int i = threadIdx.x; i < CAP; i += blockDim.x) {
        u64 k;
        if (rep) {
            k = (i < PRE_K) ? cseg[i] : 0ull;
        } else {
            u32 s = (u32)i >> 7, slot = (u32)i & 127u;
            u32 n = cnt[bc * NSH + s]; if (n > (u32)SCAP) n = SCAP;
            k = (slot < n) ? cseg[s * SCAP + slot] : 0ull;
        }
        keys[i] = k;
    }
    __syncthreads();

    bitonic_desc_1024(keys);

    for (int i = threadIdx.x; i < PRE_K * 7; i += blockDim.x) supp[i / 7][i % 7] = 0u;
    if (threadIdx.x < 7) keepw[threadIdx.x] = 0u;
    __syncthreads();

    if (threadIdx.x < PRE_K) {
        int r   = threadIdx.x;
        u64 key = keys[r];
        float sig = __uint_as_float((u32)(key >> 32));
        int a = (int)(~(u32)key);
        float4 bx = make_float4(0.f, 0.f, 0.f, 0.f);
        float ar = 0.f;
        if (sig > 0.05f) {  // valid = sc > CONF_THR
            float4 dd = *(const float4*)(pred + ((long)b * NA + a) * NCH);
            decode_box(dd, a, &bx, &ar);
            atomicOr(&keepw[r >> 5], 1u << (r & 31));
        }
        box[r] = bx; area[r] = ar;
    }
    __syncthreads();

    // suppression bitmask: bit j set for pairs j>i with IoU>0.5
    for (int p = threadIdx.x; p < PRE_K * PRE_K; p += blockDim.x) {
        int i  = p / PRE_K;
        int jx = p - i * PRE_K;
        if (jx > i) {
            float4 bi = box[i], bj = box[jx];
            float ltx = fmaxf(bi.x, bj.x), lty = fmaxf(bi.y, bj.y);
            float rbx = fminf(bi.z, bj.z), rby = fminf(bi.w, bj.w);
            float wx = fmaxf(__fsub_rn(rbx, ltx), 0.f);
            float wy = fmaxf(__fsub_rn(rby, lty), 0.f);
            float inter = __fmul_rn(wx, wy);
            float den = __fadd_rn(__fsub_rn(__fadd_rn(area[i], area[jx]), inter), 1e-8f);
            float iou = __fdiv_rn(inter, den);
            if (iou > 0.5f) atomicOr(&supp[i][jx >> 5], 1u << (jx & 31));
        }
    }
    __syncthreads();

    // serial greedy sweep (matches fori_loop exactly)
    if (threadIdx.x == 0) {
        u32 kw[7];
#pragma unroll
        for (int w = 0; w < 7; ++w) kw[w] = keepw[w];
        for (int i = 0; i < PRE_K; ++i) {
            if ((kw[i >> 5] >> (i & 31)) & 1u) {
#pragma unroll
                for (int w = 0; w < 7; ++w) kw[w] &= ~supp[i][w];
            }
        }
#pragma unroll
        for (int w = 0; w < 7; ++w) keepw[w] = kw[w];
    }
    __syncthreads();

    // ordered compaction -> per-class top-100
    if (threadIdx.x < PRE_K) {
        int r = threadIdx.x;
        if ((keepw[r >> 5] >> (r & 31)) & 1u) {
            int pos = 0;
            for (int w = 0; w < (r >> 5); ++w) pos += __popc(keepw[w]);
            pos += __popc(keepw[r >> 5] & ((1u << (r & 31)) - 1u));
            if (pos < MAXPC) {
                u64 key = keys[r];
                float sig = __uint_as_float((u32)(key >> 32));
                sc2[bc * MAXPC + pos] = sig;
                float4 bx = box[r];
                float* o = bb2 + ((long)bc * MAXPC + pos) * 4;
                o[0] = bx.x; o[1] = bx.y; o[2] = bx.z; o[3] = bx.w;
            }
        }
    }
}

// ---------- kernel 4: per-image final top-100 + outputs ----------

__global__ __launch_bounds__(1024) void k_final(const float* __restrict__ sc2,
                                                const float* __restrict__ bb2,
                                                float* __restrict__ out) {
    int b = blockIdx.x;
    __shared__ u32 hist[256];
    __shared__ u64 keys[CAP];
    __shared__ u32 cnt_s;
    __shared__ int t_s;
    for (int i = threadIdx.x; i < 256; i += blockDim.x) hist[i] = 0u;
    if (threadIdx.x == 0) cnt_s = 0u;
    __syncthreads();

    const float* s_b = sc2 + b * (NC * MAXPC);
    for (int f = threadIdx.x; f < NC * MAXPC; f += blockDim.x) {
        float s = s_b[f];
        if (s > 0.f) {
            int bin = (int)(s * 256.f); if (bin > 255) bin = 255;
            atomicAdd(&hist[bin], 1u);
        }
    }
    __syncthreads();
    if (threadIdx.x == 0) {
        u32 cum = 0; int t = 0;
        for (int bin = 255; bin >= 0; --bin) {
            cum += hist[bin];
            if (cum >= (u32)MAXDET) { t = bin; break; }
        }
        t_s = t;
    }
    __syncthreads();
    int t = t_s;
    for (int f = threadIdx.x; f < NC * MAXPC; f += blockDim.x) {
        float s = s_b[f];
        if (s > 0.f) {
            int bin = (int)(s * 256.f); if (bin > 255) bin = 255;
            if (bin >= t) {
                u32 pos = atomicAdd(&cnt_s, 1u);
                if (pos < CAP)
                    keys[pos] = ((u64)__float_as_uint(s) << 32) | (u64)(~(u32)f);
            }
        }
    }
    __syncthreads();
    u32 g = cnt_s; if (g > (u32)CAP) g = CAP;
    for (int i = threadIdx.x; i < CAP; i += blockDim.x)
        if (i >= (int)g) keys[i] = 0ull;
    __syncthreads();

    bitonic_desc_1024(keys);

    if (threadIdx.x < MAXDET) {
        int r = threadIdx.x;
        u64 key = keys[r];
        u32 hi = (u32)(key >> 32);
        if (hi != 0u) {
            float s = __uint_as_float(hi);
            int f = (int)(~(u32)key);
            int c = f / MAXPC, jj = f - c * MAXPC;
            const float* bsrc = bb2 + ((long)(b * NC + c) * MAXPC + jj) * 4;
            float* ob = out + ((long)b * MAXDET + r) * 4;
            ob[0] = bsrc[0]; ob[1] = bsrc[1]; ob[2] = bsrc[2]; ob[3] = bsrc[3];
            out[NB * MAXDET * 4 + b * MAXDET + r] = s;
            out[NB * MAXDET * 4 + NB * MAXDET + b * MAXDET + r] = (float)c;
        }
    }
    __syncthreads();
    if (threadIdx.x == 0) {
        int nv = 0;
        for (int r = 0; r < MAXDET; ++r)
            if ((u32)(keys[r] >> 32) != 0u) ++nv;
        out[NB * MAXDET * 4 + 2 * NB * MAXDET + b] = (float)nv;
    }
}

// ---------- launcher ----------

extern "C" void kernel_launch(void* const* d_in, const int* in_sizes, int n_in,
                              void* d_out, int out_size, void* d_ws, size_t ws_size,
                              hipStream_t stream) {
    // inputs: images [8,640,640,3] (unused), predictions [8,76725,84]
    const float* pred = (const float*)d_in[1];
    if (n_in >= 2 && in_sizes[0] == NB * NA * NCH) pred = (const float*)d_in[0];

    char* ws = (char*)d_ws;
    const long BCN = (long)NB * NC;
    u64* cand  = (u64*)ws;                                    // 640*8*128*8 = 5,242,880 B
    char* p    = ws + BCN * NSH * SCAP * 8;
    u32* cnt   = (u32*)p;            p += BCN * NSH * 4;      // 20,480 B
    u32* rflag = (u32*)p;            p += BCN * 4;            // 2,560 B
    float* sc2 = (float*)p;          p += BCN * MAXPC * 4;    // 256,000 B
    float* bb2 = (float*)p;                                   // 1,024,000 B

    size_t zero_bytes = (size_t)BCN * NSH * 4 + (size_t)BCN * 4
                      + (size_t)BCN * MAXPC * 4 + (size_t)BCN * MAXPC * 16;
    hipMemsetAsync(cnt, 0, zero_bytes, stream);
    hipMemsetAsync(d_out, 0, (size_t)out_size * 4, stream);

    k_scan  <<<dim3(BLKX, NB), 256, 0, stream>>>((const float4*)pred, cand, cnt);
    k_repair<<<dim3(NB * NC),  256, 0, stream>>>(pred, cand, cnt, rflag);
    k_nms   <<<dim3(NB * NC), 1024, 0, stream>>>(pred, cand, cnt, rflag, sc2, bb2);
    k_final <<<dim3(NB),      1024, 0, stream>>>(sc2, bb2, (float*)d_out);
}

// Round 4
// 152.477 us; speedup vs baseline: 2.2676x; 1.1642x over previous
//
#include <hip/hip_runtime.h>
#include <stdint.h>

typedef unsigned long long u64;
typedef unsigned int u32;

#define NB 8
#define NA 76725
#define NC 80
#define NCH 84
#define PRE_K 200
#define CAP 1024
#define T0 0.92f
#define XCUT 2.40f
#define MAXPC 100
#define MAXDET 100
#define F4_PER_IMG (NA * 21u)   // 1,611,225 float4 per image

#define NSH 8                   // counter shards per (b,c)
#define SCAP 128                // slots per shard  (8*128 = 1024 = CAP)
#define LCAP 24                 // LDS per-class list cap per block
#define BLKX 128                // blocks per image
#define SPAN (BLKX * 256u)      // grid-stride span in float4
#define FULLS8 6                // 6 * 8 * SPAN = 1,572,864 <= F4_PER_IMG

// ---------- helpers ----------

__device__ __forceinline__ float sigmoid_ref(float x) {
    // match jax.nn.sigmoid = 1/(1+exp(-x)) in fp32 (no fast-math approx)
    return 1.0f / (1.0f + expf(-x));
}

// Decode one box exactly like the reference (fp32 ops, no fma contraction;
// anchor dims in double like the python host math, then cast to f32).
__device__ void decode_box(float4 d, int a, float4* box, float* areaOut) {
    int lvl, off, fw, stride;
    if (a < 57600)      { lvl = 0; off = 0;     fw = 80; stride = 8;   }
    else if (a < 72000) { lvl = 1; off = 57600; fw = 40; stride = 16;  }
    else if (a < 75600) { lvl = 2; off = 72000; fw = 20; stride = 32;  }
    else if (a < 76500) { lvl = 3; off = 75600; fw = 10; stride = 64;  }
    else                { lvl = 4; off = 76500; fw = 5;  stride = 128; }
    int idx  = a - off;
    int k    = idx % 9;
    int cell = idx / 9;
    int row = cell / fw, col = cell - row * fw;
    float cx = __fmul_rn((float)col + 0.5f, (float)stride);
    float cy = __fmul_rn((float)row + 0.5f, (float)stride);
    int ri = k / 3, si = k - ri * 3;
    double r    = (ri == 0) ? 0.5 : ((ri == 1) ? 1.0 : 2.0);
    double side = (double)(32 << lvl);
    double area = side * side;
    double h = sqrt(area / r);
    double w = area / h;
    double s = exp2((double)si / 3.0);
    float aw = (float)(s * w);
    float ah = (float)(s * h);
    float b0 = __fmul_rn(d.x, 0.1f);
    float b1 = __fmul_rn(d.y, 0.1f);
    float b2 = __fmul_rn(d.z, 0.2f);
    float b3 = __fmul_rn(d.w, 0.2f);
    float ux = __fadd_rn(__fmul_rn(b0, aw), cx);
    float uy = __fadd_rn(__fmul_rn(b1, ah), cy);
    float wx = __fmul_rn(expf(b2), aw);
    float wy = __fmul_rn(expf(b3), ah);
    float hx = __fmul_rn(wx, 0.5f);
    float hy = __fmul_rn(wy, 0.5f);
    float x1 = __fsub_rn(ux, hx), y1 = __fsub_rn(uy, hy);
    float x2 = __fadd_rn(ux, hx), y2 = __fadd_rn(uy, hy);
    *box = make_float4(x1, y1, x2, y2);
    *areaOut = __fmul_rn(__fsub_rn(x2, x1), __fsub_rn(y2, y1));
}

__device__ __forceinline__ void bitonic_desc_1024(u64* keys) {
    for (u32 k = 2; k <= 1024u; k <<= 1) {
        for (u32 j = k >> 1; j > 0; j >>= 1) {
            for (u32 i = threadIdx.x; i < 1024u; i += blockDim.x) {
                u32 ixj = i ^ j;
                if (ixj > i) {
                    u64 x = keys[i], y = keys[ixj];
                    if (((i & k) == 0u) ? (x < y) : (x > y)) {
                        keys[i] = y; keys[ixj] = x;
                    }
                }
            }
            __syncthreads();
        }
    }
}

// ---------- kernel 1: streaming scan, LDS-staged candidates ----------

__device__ __forceinline__ void scan4(float4 v, u32 idx, u32 b, u32 sh,
                                      u32* lhist, u64 (*llist)[LCAP],
                                      u64* __restrict__ cand,
                                      u32* __restrict__ cnt) {
    u32 a  = idx / 21u;
    u32 c4 = idx - a * 21u;
    if (c4 == 0u) return;                        // box channels
    float m = fmaxf(fmaxf(v.x, v.y), fmaxf(v.z, v.w));
    if (m <= XCUT) return;                       // sigmoid(2.4423)=0.92; 2.40 conservative
    u32 cb = c4 * 4u - 4u;
    float vv[4] = {v.x, v.y, v.z, v.w};
#pragma unroll
    for (int q = 0; q < 4; ++q) {
        if (vv[q] > XCUT) {
            float sig = sigmoid_ref(vv[q]);
            if (sig > T0) {
                u32 c = cb + (u32)q;
                u64 key = ((u64)__float_as_uint(sig) << 32) | (u64)(~a);
                u32 p = atomicAdd(&lhist[c], 1u);
                if (p < LCAP) {
                    llist[c][p] = key;
                } else {                          // rare overflow: direct global
                    u32 bcsh = (b * NC + c) * NSH + sh;
                    u32 g = atomicAdd(&cnt[bcsh], 1u);
                    if (g < SCAP) cand[(u64)bcsh * SCAP + g] = key;
                }
            }
        }
    }
}

__global__ __launch_bounds__(256) void k_scan(const float4* __restrict__ p4,
                                              u64* __restrict__ cand,
                                              u32* __restrict__ cnt) {
    __shared__ u32 lhist[NC];
    __shared__ u64 llist[NC][LCAP];
    u32 b  = blockIdx.y;
    u32 sh = blockIdx.x & (NSH - 1u);
    for (u32 c = threadIdx.x; c < NC; c += 256u) lhist[c] = 0u;
    __syncthreads();

    const float4* base = p4 + (u64)b * F4_PER_IMG;
    u32 i = blockIdx.x * 256u + threadIdx.x;
#pragma unroll 1
    for (int s = 0; s < FULLS8; ++s, i += 8u * SPAN) {
        float4 v[8];
        u32 ii[8];
#pragma unroll
        for (int q = 0; q < 8; ++q) { ii[q] = i + (u32)q * SPAN; v[q] = base[ii[q]]; }
#pragma unroll
        for (int q = 0; q < 8; ++q)
            scan4(v[q], ii[q], b, sh, lhist, llist, cand, cnt);
    }
    for (; i < F4_PER_IMG; i += SPAN)
        scan4(base[i], i, b, sh, lhist, llist, cand, cnt);
    __syncthreads();

    // flush: one global atomic per touched class
    for (u32 c = threadIdx.x; c < NC; c += 256u) {
        u32 n = lhist[c]; if (n > LCAP) n = LCAP;
        if (n) {
            u32 bcsh = (b * NC + c) * NSH + sh;
            u32 base0 = atomicAdd(&cnt[bcsh], n);
            u64* seg = cand + (u64)bcsh * SCAP;
            for (u32 j = 0; j < n; ++j) {
                u32 p = base0 + j;
                if (p < SCAP) seg[p] = llist[c][j];
            }
        }
    }
}

// ---------- kernel 2: gate + (rare) exact repair + sort + NMS + top-100 ----------

__global__ __launch_bounds__(512) void k_nms(const float* __restrict__ pred,
                                             const u64* __restrict__ cand,
                                             const u32* __restrict__ cnt,
                                             float* __restrict__ sc2,
                                             float* __restrict__ bb2) {
    int bc = blockIdx.x;
    int b  = bc / NC;
    __shared__ u64 keys[CAP];
    __shared__ float4 box[PRE_K];
    __shared__ float area[PRE_K];
    __shared__ u32 supp[PRE_K][7];
    __shared__ u32 keepw[7];
    __shared__ u64 red[512];

    // gate: all shards within cap AND total >= PRE_K  -> fast path exact
    u32 total = 0; bool over = false;
    const u64* cseg = cand + (u64)bc * (NSH * SCAP);
#pragma unroll
    for (int s = 0; s < NSH; ++s) {
        u32 n = cnt[bc * NSH + s];
        if (n > (u32)SCAP) over = true;
        total += n;
    }
    bool repaired = over || (total < (u32)PRE_K);

    if (!repaired) {
        for (int i = threadIdx.x; i < CAP; i += blockDim.x) {
            u32 s = (u32)i >> 7, slot = (u32)i & 127u;
            u32 n = cnt[bc * NSH + s];
            keys[i] = (slot < n) ? cseg[s * SCAP + slot] : 0ull;
        }
        __syncthreads();
        bitonic_desc_1024(keys);
    } else {
        // exact argmax-extraction top-200 (never taken for this input; exact)
        int c = bc % NC;
        u64 cur = ~0ull;
        for (int k = 0; k < PRE_K; ++k) {
            u64 loc = 0;
            for (int a = threadIdx.x; a < NA; a += blockDim.x) {
                float x  = pred[((long)b * NA + a) * NCH + 4 + c];
                float sg = sigmoid_ref(x);
                u64 key  = ((u64)__float_as_uint(sg) << 32) | (u64)(~(u32)a);
                if (key < cur && key > loc) loc = key;
            }
            red[threadIdx.x] = loc;
            __syncthreads();
            for (int s = 256; s > 0; s >>= 1) {
                if (threadIdx.x < (u32)s) {
                    if (red[threadIdx.x + s] > red[threadIdx.x])
                        red[threadIdx.x] = red[threadIdx.x + s];
                }
                __syncthreads();
            }
            cur = red[0];
            if (threadIdx.x == 0) keys[k] = cur;
            __syncthreads();
        }
        for (int i = PRE_K + threadIdx.x; i < CAP; i += blockDim.x) keys[i] = 0ull;
        __syncthreads();
    }

    for (int i = threadIdx.x; i < PRE_K * 7; i += blockDim.x) supp[i / 7][i % 7] = 0u;
    if (threadIdx.x < 7) keepw[threadIdx.x] = 0u;
    __syncthreads();

    if (threadIdx.x < PRE_K) {
        int r   = threadIdx.x;
        u64 key = keys[r];
        float sig = __uint_as_float((u32)(key >> 32));
        int a = (int)(~(u32)key);
        float4 bx = make_float4(0.f, 0.f, 0.f, 0.f);
        float ar = 0.f;
        if (sig > 0.05f) {  // valid = sc > CONF_THR
            float4 dd = *(const float4*)(pred + ((long)b * NA + a) * NCH);
            decode_box(dd, a, &bx, &ar);
            atomicOr(&keepw[r >> 5], 1u << (r & 31));
        }
        box[r] = bx; area[r] = ar;
    }
    __syncthreads();

    // suppression bitmask: bit j set for pairs j>i with IoU>0.5
    for (int p = threadIdx.x; p < PRE_K * PRE_K; p += blockDim.x) {
        int i  = p / PRE_K;
        int jx = p - i * PRE_K;
        if (jx > i) {
            float4 bi = box[i], bj = box[jx];
            float ltx = fmaxf(bi.x, bj.x), lty = fmaxf(bi.y, bj.y);
            float rbx = fminf(bi.z, bj.z), rby = fminf(bi.w, bj.w);
            float wx = fmaxf(__fsub_rn(rbx, ltx), 0.f);
            float wy = fmaxf(__fsub_rn(rby, lty), 0.f);
            float inter = __fmul_rn(wx, wy);
            float den = __fadd_rn(__fsub_rn(__fadd_rn(area[i], area[jx]), inter), 1e-8f);
            float iou = __fdiv_rn(inter, den);
            if (iou > 0.5f) atomicOr(&supp[i][jx >> 5], 1u << (jx & 31));
        }
    }
    __syncthreads();

    // serial greedy sweep (matches fori_loop exactly)
    if (threadIdx.x == 0) {
        u32 kw[7];
#pragma unroll
        for (int w = 0; w < 7; ++w) kw[w] = keepw[w];
        for (int i = 0; i < PRE_K; ++i) {
            if ((kw[i >> 5] >> (i & 31)) & 1u) {
#pragma unroll
                for (int w = 0; w < 7; ++w) kw[w] &= ~supp[i][w];
            }
        }
#pragma unroll
        for (int w = 0; w < 7; ++w) keepw[w] = kw[w];
    }
    __syncthreads();

    // full write of per-class top-100 (zero-fill; no memset dependency)
    int kept = 0;
#pragma unroll
    for (int w = 0; w < 7; ++w) kept += __popc(keepw[w]);
    if (kept > MAXPC) kept = MAXPC;

    if (threadIdx.x >= (u32)kept && threadIdx.x < MAXPC) {
        int pos = threadIdx.x;
        sc2[bc * MAXPC + pos] = 0.f;
        float* o = bb2 + ((long)bc * MAXPC + pos) * 4;
        o[0] = 0.f; o[1] = 0.f; o[2] = 0.f; o[3] = 0.f;
    }
    if (threadIdx.x < PRE_K) {
        int r = threadIdx.x;
        if ((keepw[r >> 5] >> (r & 31)) & 1u) {
            int pos = 0;
            for (int w = 0; w < (r >> 5); ++w) pos += __popc(keepw[w]);
            pos += __popc(keepw[r >> 5] & ((1u << (r & 31)) - 1u));
            if (pos < MAXPC) {
                u64 key = keys[r];
                float sig = __uint_as_float((u32)(key >> 32));
                sc2[bc * MAXPC + pos] = sig;
                float4 bx = box[r];
                float* o = bb2 + ((long)bc * MAXPC + pos) * 4;
                o[0] = bx.x; o[1] = bx.y; o[2] = bx.z; o[3] = bx.w;
            }
        }
    }
}

// ---------- kernel 3: per-image final top-100 + full output write ----------

__global__ __launch_bounds__(1024) void k_final(const float* __restrict__ sc2,
                                                const float* __restrict__ bb2,
                                                float* __restrict__ out) {
    int b = blockIdx.x;
    __shared__ u32 hist[256];
    __shared__ u64 keys[CAP];
    __shared__ u32 cnt_s;
    __shared__ int t_s;
    for (int i = threadIdx.x; i < 256; i += blockDim.x) hist[i] = 0u;
    if (threadIdx.x == 0) cnt_s = 0u;
    __syncthreads();

    const float* s_b = sc2 + b * (NC * MAXPC);
    for (int f = threadIdx.x; f < NC * MAXPC; f += blockDim.x) {
        float s = s_b[f];
        if (s > 0.f) {
            int bin = (int)(s * 256.f); if (bin > 255) bin = 255;
            atomicAdd(&hist[bin], 1u);
        }
    }
    __syncthreads();
    if (threadIdx.x == 0) {
        u32 cum = 0; int t = 0;
        for (int bin = 255; bin >= 0; --bin) {
            cum += hist[bin];
            if (cum >= (u32)MAXDET) { t = bin; break; }
        }
        t_s = t;
    }
    __syncthreads();
    int t = t_s;
    for (int f = threadIdx.x; f < NC * MAXPC; f += blockDim.x) {
        float s = s_b[f];
        if (s > 0.f) {
            int bin = (int)(s * 256.f); if (bin > 255) bin = 255;
            if (bin >= t) {
                u32 pos = atomicAdd(&cnt_s, 1u);
                if (pos < CAP)
                    keys[pos] = ((u64)__float_as_uint(s) << 32) | (u64)(~(u32)f);
            }
        }
    }
    __syncthreads();
    u32 g = cnt_s; if (g > (u32)CAP) g = CAP;
    for (int i = threadIdx.x; i < CAP; i += blockDim.x)
        if (i >= (int)g) keys[i] = 0ull;
    __syncthreads();

    bitonic_desc_1024(keys);

    if (threadIdx.x < MAXDET) {
        int r = threadIdx.x;
        u64 key = keys[r];
        u32 hi = (u32)(key >> 32);
        float s = 0.f, cf = 0.f;
        float bx0 = 0.f, bx1 = 0.f, bx2 = 0.f, bx3 = 0.f;
        if (hi != 0u) {
            s = __uint_as_float(hi);
            int f = (int)(~(u32)key);
            int c = f / MAXPC, jj = f - c * MAXPC;
            const float* bsrc = bb2 + ((long)(b * NC + c) * MAXPC + jj) * 4;
            bx0 = bsrc[0]; bx1 = bsrc[1]; bx2 = bsrc[2]; bx3 = bsrc[3];
            cf = (float)c;
        }
        float* ob = out + ((long)b * MAXDET + r) * 4;
        ob[0] = bx0; ob[1] = bx1; ob[2] = bx2; ob[3] = bx3;
        out[NB * MAXDET * 4 + b * MAXDET + r] = s;
        out[NB * MAXDET * 4 + NB * MAXDET + b * MAXDET + r] = cf;
    }
    __syncthreads();
    if (threadIdx.x == 0) {
        int nv = 0;
        for (int r = 0; r < MAXDET; ++r)
            if ((u32)(keys[r] >> 32) != 0u) ++nv;
        out[NB * MAXDET * 4 + 2 * NB * MAXDET + b] = (float)nv;
    }
}

// ---------- launcher ----------

extern "C" void kernel_launch(void* const* d_in, const int* in_sizes, int n_in,
                              void* d_out, int out_size, void* d_ws, size_t ws_size,
                              hipStream_t stream) {
    // inputs: images [8,640,640,3] (unused), predictions [8,76725,84]
    const float* pred = (const float*)d_in[1];
    if (n_in >= 2 && in_sizes[0] == NB * NA * NCH) pred = (const float*)d_in[0];

    char* ws = (char*)d_ws;
    const long BCN = (long)NB * NC;
    u64* cand  = (u64*)ws;                                    // 640*8*128*8 = 5,242,880 B
    char* p    = ws + BCN * NSH * SCAP * 8;
    u32* cnt   = (u32*)p;            p += BCN * NSH * 4;      // 20,480 B
    float* sc2 = (float*)p;          p += BCN * MAXPC * 4;    // 256,000 B
    float* bb2 = (float*)p;                                   // 1,024,000 B

    hipMemsetAsync(cnt, 0, (size_t)BCN * NSH * 4, stream);

    k_scan <<<dim3(BLKX, NB), 256, 0, stream>>>((const float4*)pred, cand, cnt);
    k_nms  <<<dim3(NB * NC),  512, 0, stream>>>(pred, cand, cnt, sc2, bb2);
    k_final<<<dim3(NB),      1024, 0, stream>>>(sc2, bb2, (float*)d_out);
}